// Round 6
// baseline (675.510 us; speedup 1.0000x reference)
//
#include <hip/hip_runtime.h>
#include <hip/hip_cooperative_groups.h>

namespace cg = cooperative_groups;

// CapsNet dynamic routing via bf16 MFMA (v_mfma_f32_32x32x16_bf16).
// Shapes: x[64][2048][16], kernel[2048][32][16][32], out V[64][32][32], fp32 in/out.
//
// Round-6: ONE persistent cooperative kernel runs all 3 routing iterations and
// the global S-reduce/squash (5 grid.sync()s), replacing 9 launches. Grid =
// 256 blocks x 512 thr = exactly 1 block/CU at 2 waves/SIMD (launch_bounds
// (512,2); round-4 lesson: never tighten below actual VGPR demand -> spills).
// conv_k / conv_x stage bf16 MFMA fragments once.

#define NIN   2048
#define DIN   16
#define NOUT  32
#define DOUT  32
#define NTILE 16
#define NB    (NIN/NTILE)   // 128

typedef __attribute__((ext_vector_type(8)))  short s16x8;
typedef __attribute__((ext_vector_type(16))) float f32x16;

// ws float offsets
#define WS_BLOG   0                        // 64*2048*32        = 4194304 f
#define WS_SPART  4194304                  // 256 * 32768       = 8388608 f
#define WS_V      12582912                 // 65536 f
#define WS_KTF    12648448                 // 2048*32*64*8 bf16 = 16777216 f-equiv
#define WS_XTF    29425664                 // 2*2048*64*8 bf16  = 1048576 f-equiv
// total = 30,474,240 floats ~= 122 MB

__device__ __forceinline__ unsigned short f2bf(float f) {
  unsigned u = __float_as_uint(f);
  u = (u + 0x7fffu + ((u >> 16) & 1u)) >> 16;
  return (unsigned short)u;
}

// Repack kernel[n][j][k][d] fp32 -> Ktf[n][d][lane][i] bf16 via LDS transpose.
// B-fragment convention: col j = lane&31, k = (lane>>5)*8 + i  (same as A's).
__global__ __launch_bounds__(256) void conv_k(const float* __restrict__ Kr,
                                              unsigned short* __restrict__ Ktf) {
  const int n = blockIdx.x;
  const int t = threadIdx.x;
  __shared__ float kl[16384];               // 64 KB: K[n] swizzled (d-quad ^ j&7)
  const float* src = Kr + (size_t)n * 16384;
#pragma unroll
  for (int c = 0; c < 16; ++c) {
    const int idx = (c * 256 + t) * 4;      // linear dword idx = j*512 + k*32 + d
    const int jj  = idx >> 9;
    const int sidx = (idx & ~28) | (((((idx >> 2) & 7) ^ (jj & 7))) << 2);
    *(float4*)&kl[sidx] = *(const float4*)(src + idx);
  }
  __syncthreads();
  unsigned short* dst = Ktf + (size_t)n * 16384;
#pragma unroll
  for (int c = 0; c < 8; ++c) {
    const int chunk = c * 256 + t;          // (d, lane)
    const int d = chunk >> 6, lane = chunk & 63;
    const int j = lane & 31, khi = lane >> 5;
    const int dsw = ((((d >> 2) ^ (j & 7)) << 2)) | (d & 3);
    unsigned short u8[8];
#pragma unroll
    for (int i = 0; i < 8; ++i)
      u8[i] = f2bf(kl[j * 512 + (khi * 8 + i) * 32 + dsw]);
    uint4 o;
    o.x = u8[0] | ((unsigned)u8[1] << 16);
    o.y = u8[2] | ((unsigned)u8[3] << 16);
    o.z = u8[4] | ((unsigned)u8[5] << 16);
    o.w = u8[6] | ((unsigned)u8[7] << 16);
    *(uint4*)(dst + (size_t)chunk * 8) = o;
  }
}

// x[b][n][k] fp32 -> xtf[bh][n][lane][i] bf16; A-frag: row b = lane&31, k = (lane>>5)*8+i
__global__ __launch_bounds__(256) void conv_x(const float* __restrict__ x,
                                              unsigned short* __restrict__ xtf) {
  const int g = blockIdx.x * 256 + threadIdx.x;   // 262144 chunks
  const int bh = g >> 17, rem = g & 131071;
  const int n = rem >> 6, lane = rem & 63;
  const int b = bh * 32 + (lane & 31), khi = lane >> 5;
  const float* src = x + ((size_t)b * NIN + n) * DIN + khi * 8;
  unsigned short u8[8];
#pragma unroll
  for (int i = 0; i < 8; ++i) u8[i] = f2bf(src[i]);
  uint4 o;
  o.x = u8[0] | ((unsigned)u8[1] << 16);
  o.y = u8[2] | ((unsigned)u8[3] << 16);
  o.z = u8[4] | ((unsigned)u8[5] << 16);
  o.w = u8[6] | ((unsigned)u8[7] << 16);
  *(uint4*)(xtf + (size_t)g * 8) = o;
}

// Persistent cooperative kernel: all 3 routing iterations.
// it=0: C = 1/32 uniform. it=1: Blog = U.V (write), C = softmax.
// it=2: l = Blog + U.V (read), C = softmax.
// Block: 512 thr = 8 waves; wave w owns d in [4w, 4w+4). blk = bh*128 + nt.
// C/D layout (verified): col j = lane&31, row b = (r&3) + 4*(lane>>5) + 8*(r>>2).
__global__ __launch_bounds__(512, 2) void caps_persist(
    const unsigned short* __restrict__ Ktf, const unsigned short* __restrict__ xtf,
    float* __restrict__ Blog, float* __restrict__ Spart,
    float* __restrict__ Vbuf, float* __restrict__ Out)
{
  cg::grid_group grid = cg::this_grid();
  const int tid = threadIdx.x;
  const int w = tid >> 6, lane = tid & 63;
  const int j = lane & 31, hi = lane >> 5;
  const int blk = blockIdx.x;
  const int nt = blk & 127, bh = blk >> 7;
  const int n0 = nt * NTILE;

  __shared__ float Ds[8][32][32];   // per-wave partial dots [w][b][j]
  __shared__ float Cs[32][32];      // softmax coefficients [b][j]

  const int rb = tid >> 5;          // phase-C b0 (0..15); b1 = rb+16
  const int rj = tid & 31;
  const int gtid = blk * 512 + tid;

#pragma unroll 1
  for (int it = 0; it < 3; ++it) {
    float sacc[16][4];
#pragma unroll
    for (int r = 0; r < 16; ++r)
#pragma unroll
      for (int dd = 0; dd < 4; ++dd) sacc[r][dd] = 0.f;

    float vreg[16][4];              // V[b(r,hi)][j][4w+dd], loaded once per iter
    if (it != 0) {
#pragma unroll
      for (int r = 0; r < 16; ++r) {
        const int b = (r & 3) + 4 * hi + 8 * (r >> 2);
        const float4 v4 = *(const float4*)(Vbuf + (((size_t)(bh * 32 + b) * 32 + j) * 32 + w * 4));
        vreg[r][0] = v4.x; vreg[r][1] = v4.y; vreg[r][2] = v4.z; vreg[r][3] = v4.w;
      }
    }

    // fragment pointers (stride per n: xtf 512 shorts, Ktf 16384 shorts)
    const unsigned short* xp = xtf + (((size_t)bh * NIN + n0) * 64 + lane) * 8;
    const unsigned short* kp = Ktf + (((size_t)n0 * 32 + w * 4) * 64 + lane) * 8;

    // preload n0 fragments
    s16x8 a = *(const s16x8*)xp;
    s16x8 bf[4];
#pragma unroll
    for (int dd = 0; dd < 4; ++dd) bf[dd] = *(const s16x8*)(kp + dd * 512);

#pragma unroll 1
    for (int nn = 0; nn < NTILE; ++nn) {
      const int n = n0 + nn;

      f32x16 u[4];
#pragma unroll
      for (int dd = 0; dd < 4; ++dd) {
        f32x16 z;
#pragma unroll
        for (int q = 0; q < 16; ++q) z[q] = 0.f;
        u[dd] = __builtin_amdgcn_mfma_f32_32x32x16_bf16(a, bf[dd], z, 0, 0, 0);
      }

      // prefetch n+1 fragments (issued before the barriers; hides under C/E)
      const int inc = (nn < NTILE - 1) ? 1 : 0;
      const s16x8 a2 = *(const s16x8*)(xp + inc * 512);
      s16x8 bf2[4];
#pragma unroll
      for (int dd = 0; dd < 4; ++dd)
        bf2[dd] = *(const s16x8*)(kp + inc * 16384 + dd * 512);
      xp += inc * 512;
      kp += inc * 16384;

      if (it == 0) {
#pragma unroll
        for (int r = 0; r < 16; ++r)
#pragma unroll
          for (int dd = 0; dd < 4; ++dd)
            sacc[r][dd] = fmaf(0.03125f, u[dd][r], sacc[r][dd]);
      } else {
        // per-wave partial dot over its 4 d's -> Ds[w][b][j] (bank = j, conflict-free)
#pragma unroll
        for (int r = 0; r < 16; ++r) {
          const float pd = u[0][r] * vreg[r][0] + u[1][r] * vreg[r][1]
                         + u[2][r] * vreg[r][2] + u[3][r] * vreg[r][3];
          const int b = (r & 3) + 4 * hi + 8 * (r >> 2);
          Ds[w][b][j] = pd;
        }
        __syncthreads();
        // full dot = sum over 8 waves; Blog update; in-wave softmax over j
        // (no max-sub: |logit| <= ~6, exp safe in fp32, mathematically identical)
        float l0 = 0.f, l1 = 0.f;
#pragma unroll
        for (int ww = 0; ww < 8; ++ww) { l0 += Ds[ww][rb][rj]; l1 += Ds[ww][rb + 16][rj]; }
        const size_t bi0 = ((size_t)(bh * 32 + rb) * NIN + n) * 32 + rj;
        const size_t bi1 = ((size_t)(bh * 32 + rb + 16) * NIN + n) * 32 + rj;
        if (it == 1) { Blog[bi0] = l0; Blog[bi1] = l1; }
        else         { l0 += Blog[bi0]; l1 += Blog[bi1]; }
        const float e0 = __expf(l0), e1 = __expf(l1);
        float s0 = e0, s1 = e1;
#pragma unroll
        for (int mm = 16; mm >= 1; mm >>= 1) {
          s0 += __shfl_xor(s0, mm, 64);
          s1 += __shfl_xor(s1, mm, 64);
        }
        Cs[rb][rj]      = __fdividef(e0, s0);
        Cs[rb + 16][rj] = __fdividef(e1, s1);
        __syncthreads();
        // S += C * U   (Cs read: bank = j, conflict-free)
#pragma unroll
        for (int r = 0; r < 16; ++r) {
          const int b = (r & 3) + 4 * hi + 8 * (r >> 2);
          const float c = Cs[b][j];
#pragma unroll
          for (int dd = 0; dd < 4; ++dd) sacc[r][dd] = fmaf(c, u[dd][r], sacc[r][dd]);
        }
      }

      a = a2;
#pragma unroll
      for (int dd = 0; dd < 4; ++dd) bf[dd] = bf2[dd];
    }

    // write per-block partial S: Spart[bh*NB+nt][b][j][d]
    float* Sp = Spart + (size_t)blk * 32768;
#pragma unroll
    for (int r = 0; r < 16; ++r) {
      const int b = (r & 3) + 4 * hi + 8 * (r >> 2);
      *(float4*)(Sp + ((size_t)b * 32 + j) * 32 + w * 4) =
          make_float4(sacc[r][0], sacc[r][1], sacc[r][2], sacc[r][3]);
    }

    grid.sync();

    // global reduce over the 128 n-tiles of this element's bh, then squash.
    // gtid < 65536 covers all [b][j][d]; loads coalesced (consecutive gtid ->
    // consecutive addresses within a tile).
    if (gtid < 65536) {
      const int bhe = gtid >> 15;
      const int ei  = gtid & 32767;
      const float* base = Spart + (size_t)(bhe * NB) * 32768 + ei;
      float s = 0.f;
#pragma unroll 8
      for (int t = 0; t < NB; ++t) s += base[(size_t)t * 32768];
      float sq = s * s;
#pragma unroll
      for (int m = 16; m >= 1; m >>= 1) sq += __shfl_xor(sq, m, 64);
      const float v = s * (sq / (1.0f + sq)) * rsqrtf(sq + 1e-8f);
      if (it < 2) Vbuf[gtid] = v;
      else        Out[gtid]  = v;
    }
    if (it < 2) grid.sync();   // Vbuf ready + Spart free to overwrite
  }
}

extern "C" void kernel_launch(void* const* d_in, const int* in_sizes, int n_in,
                              void* d_out, int out_size, void* d_ws, size_t ws_size,
                              hipStream_t stream) {
  const float* x  = (const float*)d_in[0];
  const float* Kr = (const float*)d_in[1];
  float* ws = (float*)d_ws;
  float* Blog  = ws + WS_BLOG;
  float* Spart = ws + WS_SPART;
  float* Vbuf  = ws + WS_V;
  unsigned short* Ktf = (unsigned short*)(ws + WS_KTF);
  unsigned short* xtf = (unsigned short*)(ws + WS_XTF);
  float* out = (float*)d_out;

  conv_k<<<NIN, 256, 0, stream>>>(Kr, Ktf);
  conv_x<<<1024, 256, 0, stream>>>(x, xtf);

  void* args[] = { (void*)&Ktf, (void*)&xtf, (void*)&Blog, (void*)&Spart,
                   (void*)&Vbuf, (void*)&out };
  hipLaunchCooperativeKernel((void*)caps_persist, dim3(256), dim3(512),
                             args, 0, stream);
}

// Round 7
// 367.753 us; speedup vs baseline: 1.8369x; 1.8369x over previous
//
#include <hip/hip_runtime.h>

// CapsNet dynamic routing via bf16 MFMA (v_mfma_f32_32x32x16_bf16).
// Shapes: x[64][2048][16], kernel[2048][32][16][32], out V[64][32][32], fp32 in/out.
//
// Round-7: round-5 separate-launch structure (fusion regressed: r6 675us) +
// (1) RAW barriers (lgkmcnt(0) + s_barrier, no vmcnt drain -> prefetch survives),
// (2) XCD twin-swizzle (bh-pairs share an nt's 512KB Ktf slice -> same-XCD L2),
// (3) MODE0 2-deep ping-pong pipeline (barrier-free pass).
// Round-4 lesson: never tighten launch_bounds below VGPR demand (spill = 6x).

#define NIN   2048
#define DIN   16
#define NOUT  32
#define DOUT  32
#define NTILE 16
#define NB    (NIN/NTILE)   // 128

typedef __attribute__((ext_vector_type(8)))  short s16x8;
typedef __attribute__((ext_vector_type(16))) float f32x16;

// ws float offsets
#define WS_BLOG   0                        // 64*2048*32        = 4194304 f
#define WS_SPART  4194304                  // 256 * 32768       = 8388608 f
#define WS_SPART2 12582912                 // 8 * 65536         = 524288 f
#define WS_V      13107200                 // 65536 f
#define WS_KTF    13172736                 // 2048*32*64*8 bf16 = 16777216 f-equiv
#define WS_XTF    29949952                 // 2*2048*64*8 bf16  = 1048576 f-equiv
// total = 30,998,528 floats ~= 124 MB

__device__ __forceinline__ unsigned short f2bf(float f) {
  unsigned u = __float_as_uint(f);
  u = (u + 0x7fffu + ((u >> 16) & 1u)) >> 16;
  return (unsigned short)u;
}

// raw barrier: drain LDS ops only (NOT vmcnt -- keeps global prefetch in flight)
__device__ __forceinline__ void lds_barrier() {
  asm volatile("s_waitcnt lgkmcnt(0)" ::: "memory");
  __builtin_amdgcn_sched_barrier(0);
  __builtin_amdgcn_s_barrier();
  __builtin_amdgcn_sched_barrier(0);
}

// Repack kernel[n][j][k][d] fp32 -> Ktf[n][d][lane][i] bf16 via LDS transpose.
// B-fragment convention: col j = lane&31, k = (lane>>5)*8 + i  (same as A's).
__global__ __launch_bounds__(256) void conv_k(const float* __restrict__ Kr,
                                              unsigned short* __restrict__ Ktf) {
  const int n = blockIdx.x;
  const int t = threadIdx.x;
  __shared__ float kl[16384];               // 64 KB: K[n] swizzled (d-quad ^ j&7)
  const float* src = Kr + (size_t)n * 16384;
#pragma unroll
  for (int c = 0; c < 16; ++c) {
    const int idx = (c * 256 + t) * 4;      // linear dword idx = j*512 + k*32 + d
    const int jj  = idx >> 9;
    const int sidx = (idx & ~28) | (((((idx >> 2) & 7) ^ (jj & 7))) << 2);
    *(float4*)&kl[sidx] = *(const float4*)(src + idx);
  }
  __syncthreads();
  unsigned short* dst = Ktf + (size_t)n * 16384;
#pragma unroll
  for (int c = 0; c < 8; ++c) {
    const int chunk = c * 256 + t;          // (d, lane)
    const int d = chunk >> 6, lane = chunk & 63;
    const int j = lane & 31, khi = lane >> 5;
    const int dsw = ((((d >> 2) ^ (j & 7)) << 2)) | (d & 3);
    unsigned short u8[8];
#pragma unroll
    for (int i = 0; i < 8; ++i)
      u8[i] = f2bf(kl[j * 512 + (khi * 8 + i) * 32 + dsw]);
    uint4 o;
    o.x = u8[0] | ((unsigned)u8[1] << 16);
    o.y = u8[2] | ((unsigned)u8[3] << 16);
    o.z = u8[4] | ((unsigned)u8[5] << 16);
    o.w = u8[6] | ((unsigned)u8[7] << 16);
    *(uint4*)(dst + (size_t)chunk * 8) = o;
  }
}

// x[b][n][k] fp32 -> xtf[bh][n][lane][i] bf16; A-frag: row b = lane&31, k = (lane>>5)*8+i
__global__ __launch_bounds__(256) void conv_x(const float* __restrict__ x,
                                              unsigned short* __restrict__ xtf) {
  const int g = blockIdx.x * 256 + threadIdx.x;   // 262144 chunks
  const int bh = g >> 17, rem = g & 131071;
  const int n = rem >> 6, lane = rem & 63;
  const int b = bh * 32 + (lane & 31), khi = lane >> 5;
  const float* src = x + ((size_t)b * NIN + n) * DIN + khi * 8;
  unsigned short u8[8];
#pragma unroll
  for (int i = 0; i < 8; ++i) u8[i] = f2bf(src[i]);
  uint4 o;
  o.x = u8[0] | ((unsigned)u8[1] << 16);
  o.y = u8[2] | ((unsigned)u8[3] << 16);
  o.z = u8[4] | ((unsigned)u8[5] << 16);
  o.w = u8[6] | ((unsigned)u8[7] << 16);
  *(uint4*)(xtf + (size_t)g * 8) = o;
}

// MODE 0: C = 1/32 uniform. MODE 1: Blog = U.V (write), C = softmax.
// MODE 2: l = Blog + U.V (read), C = softmax.
// Block: 512 thr = 8 waves; wave w owns d in [4w, 4w+4). Grid 256 linear blocks;
// twin-swizzle: blk = g*16 + bh*8 + r, nt = g*8+r  ->  bh twins of an nt are
// congruent mod 8 (same XCD under round-robin) and share the Ktf slice in L2.
// C/D layout (verified): col j = lane&31, row b = (r&3) + 4*(lane>>5) + 8*(r>>2).
template<int MODE>
__global__ __launch_bounds__(512, 2) void caps_mfma(
    const unsigned short* __restrict__ Ktf, const unsigned short* __restrict__ xtf,
    const float* __restrict__ Vin, float* __restrict__ Blog,
    float* __restrict__ Spart)
{
  const int tid = threadIdx.x;
  const int w = tid >> 6, lane = tid & 63;
  const int j = lane & 31, hi = lane >> 5;
  const int blk = blockIdx.x;
  const int nt = (blk >> 4) * 8 + (blk & 7);
  const int bh = (blk >> 3) & 1;
  const int n0 = nt * NTILE;

  __shared__ float Ds[8][32][32];   // per-wave partial dots [w][b][j]
  __shared__ float Cs[32][32];      // softmax coefficients [b][j]

  float sacc[16][4];
#pragma unroll
  for (int r = 0; r < 16; ++r)
#pragma unroll
    for (int dd = 0; dd < 4; ++dd) sacc[r][dd] = 0.f;

  if (MODE == 0) {
    // ---- barrier-free pass, 2-deep ping-pong pipeline ----------------------
    const unsigned short* xpA = xtf + (((size_t)bh * NIN + n0) * 64 + lane) * 8;
    const unsigned short* kpA = Ktf + (((size_t)n0 * 32 + w * 4) * 64 + lane) * 8;
    const unsigned short* xpB = xpA + 512;
    const unsigned short* kpB = kpA + 16384;

    s16x8 aA = *(const s16x8*)xpA, aB = *(const s16x8*)xpB;
    s16x8 bfA[4], bfB[4];
#pragma unroll
    for (int dd = 0; dd < 4; ++dd) {
      bfA[dd] = *(const s16x8*)(kpA + dd * 512);
      bfB[dd] = *(const s16x8*)(kpB + dd * 512);
    }

#pragma unroll 1
    for (int nn = 0; nn < NTILE; nn += 2) {
      f32x16 u[4];
#pragma unroll
      for (int dd = 0; dd < 4; ++dd) {
        f32x16 z;
#pragma unroll
        for (int q = 0; q < 16; ++q) z[q] = 0.f;
        u[dd] = __builtin_amdgcn_mfma_f32_32x32x16_bf16(aA, bfA[dd], z, 0, 0, 0);
      }
      {  // reload A <- n = nn+2 (in flight across the next ~1.5 half-iters)
        const int inc = (nn + 2 < NTILE) ? 2 : 0;
        xpA += inc * 512;  kpA += inc * 16384;
        aA = *(const s16x8*)xpA;
#pragma unroll
        for (int dd = 0; dd < 4; ++dd) bfA[dd] = *(const s16x8*)(kpA + dd * 512);
      }
#pragma unroll
      for (int r = 0; r < 16; ++r)
#pragma unroll
        for (int dd = 0; dd < 4; ++dd)
          sacc[r][dd] = fmaf(0.03125f, u[dd][r], sacc[r][dd]);

#pragma unroll
      for (int dd = 0; dd < 4; ++dd) {
        f32x16 z;
#pragma unroll
        for (int q = 0; q < 16; ++q) z[q] = 0.f;
        u[dd] = __builtin_amdgcn_mfma_f32_32x32x16_bf16(aB, bfB[dd], z, 0, 0, 0);
      }
      {  // reload B <- n = nn+3
        const int inc = (nn + 3 < NTILE) ? 2 : 0;
        xpB += inc * 512;  kpB += inc * 16384;
        aB = *(const s16x8*)xpB;
#pragma unroll
        for (int dd = 0; dd < 4; ++dd) bfB[dd] = *(const s16x8*)(kpB + dd * 512);
      }
#pragma unroll
      for (int r = 0; r < 16; ++r)
#pragma unroll
        for (int dd = 0; dd < 4; ++dd)
          sacc[r][dd] = fmaf(0.03125f, u[dd][r], sacc[r][dd]);
    }
  } else {
    // ---- softmax passes: raw barriers, 1-deep prefetch ---------------------
    float vreg[16][4];              // V[b(r,hi)][j][4w+dd], loaded once
#pragma unroll
    for (int r = 0; r < 16; ++r) {
      const int b = (r & 3) + 4 * hi + 8 * (r >> 2);
      const float4 v4 = *(const float4*)(Vin + (((size_t)(bh * 32 + b) * 32 + j) * 32 + w * 4));
      vreg[r][0] = v4.x; vreg[r][1] = v4.y; vreg[r][2] = v4.z; vreg[r][3] = v4.w;
    }

    const int rb = tid >> 5;        // phase-C b0 (0..15); b1 = rb+16
    const int rj = tid & 31;

    const unsigned short* xp = xtf + (((size_t)bh * NIN + n0) * 64 + lane) * 8;
    const unsigned short* kp = Ktf + (((size_t)n0 * 32 + w * 4) * 64 + lane) * 8;

    s16x8 a = *(const s16x8*)xp;
    s16x8 bf[4];
#pragma unroll
    for (int dd = 0; dd < 4; ++dd) bf[dd] = *(const s16x8*)(kp + dd * 512);

#pragma unroll 1
    for (int nn = 0; nn < NTILE; ++nn) {
      const int n = n0 + nn;

      f32x16 u[4];
#pragma unroll
      for (int dd = 0; dd < 4; ++dd) {
        f32x16 z;
#pragma unroll
        for (int q = 0; q < 16; ++q) z[q] = 0.f;
        u[dd] = __builtin_amdgcn_mfma_f32_32x32x16_bf16(a, bf[dd], z, 0, 0, 0);
      }

      // prefetch n+1 (stays in flight across BOTH raw barriers below)
      const int inc = (nn < NTILE - 1) ? 1 : 0;
      const s16x8 a2 = *(const s16x8*)(xp + inc * 512);
      s16x8 bf2[4];
#pragma unroll
      for (int dd = 0; dd < 4; ++dd)
        bf2[dd] = *(const s16x8*)(kp + inc * 16384 + dd * 512);
      xp += inc * 512;
      kp += inc * 16384;

      // phase A: per-wave partial dot -> Ds[w][b][j] (bank = j, conflict-free)
#pragma unroll
      for (int r = 0; r < 16; ++r) {
        const float pd = u[0][r] * vreg[r][0] + u[1][r] * vreg[r][1]
                       + u[2][r] * vreg[r][2] + u[3][r] * vreg[r][3];
        const int b = (r & 3) + 4 * hi + 8 * (r >> 2);
        Ds[w][b][j] = pd;
      }
      lds_barrier();
      // phase C: 8-wave dot sum; Blog update; in-wave softmax over j
      // (no max-sub: |logit| <= ~6, exp safe in fp32, mathematically identical)
      float l0 = 0.f, l1 = 0.f;
#pragma unroll
      for (int ww = 0; ww < 8; ++ww) { l0 += Ds[ww][rb][rj]; l1 += Ds[ww][rb + 16][rj]; }
      const size_t bi0 = ((size_t)(bh * 32 + rb) * NIN + n) * 32 + rj;
      const size_t bi1 = ((size_t)(bh * 32 + rb + 16) * NIN + n) * 32 + rj;
      if (MODE == 1) { Blog[bi0] = l0; Blog[bi1] = l1; }
      else           { l0 += Blog[bi0]; l1 += Blog[bi1]; }
      const float e0 = __expf(l0), e1 = __expf(l1);
      float s0 = e0, s1 = e1;
#pragma unroll
      for (int mm = 16; mm >= 1; mm >>= 1) {
        s0 += __shfl_xor(s0, mm, 64);
        s1 += __shfl_xor(s1, mm, 64);
      }
      Cs[rb][rj]      = __fdividef(e0, s0);
      Cs[rb + 16][rj] = __fdividef(e1, s1);
      lds_barrier();
      // phase E: S += C * U   (Cs read: bank = j, conflict-free)
#pragma unroll
      for (int r = 0; r < 16; ++r) {
        const int b = (r & 3) + 4 * hi + 8 * (r >> 2);
        const float c = Cs[b][j];
#pragma unroll
        for (int dd = 0; dd < 4; ++dd) sacc[r][dd] = fmaf(c, u[dd][r], sacc[r][dd]);
      }

      a = a2;
#pragma unroll
      for (int dd = 0; dd < 4; ++dd) bf[dd] = bf2[dd];
    }
  }

  // write per-block partial S: Spart[bh*NB+nt][b][j][d]
  float* Sp = Spart + (size_t)(bh * NB + nt) * 32768;
#pragma unroll
  for (int r = 0; r < 16; ++r) {
    const int b = (r & 3) + 4 * hi + 8 * (r >> 2);
    *(float4*)(Sp + ((size_t)b * 32 + j) * 32 + w * 4) =
        make_float4(sacc[r][0], sacc[r][1], sacc[r][2], sacc[r][3]);
  }
}

// stage 1: 8 groups of 16 tiles each; coalesced. 524288 threads.
__global__ __launch_bounds__(256) void reduce_s1(const float* __restrict__ Spart,
                                                 float* __restrict__ Spart2) {
  const int g = blockIdx.x * 256 + threadIdx.x;   // [p][bh][ei]
  const int e = g & 65535, p = g >> 16;           // p = 0..7
  const int bh = e >> 15, ei = e & 32767;
  const float* base = Spart + ((size_t)(bh * NB + p * 16)) * 32768 + ei;
  float s = 0.f;
#pragma unroll
  for (int i = 0; i < 16; ++i) s += base[(size_t)i * 32768];
  Spart2[(size_t)p * 65536 + e] = s;
}

// stage 2: finish sum (8 partials), squash over d (= lane bits 0..4), write V.
__global__ __launch_bounds__(256) void reduce_s2(const float* __restrict__ Spart2,
                                                 float* __restrict__ Vout) {
  const int t = blockIdx.x * 256 + threadIdx.x;   // [b][j][d]
  float s = 0.f;
#pragma unroll
  for (int p = 0; p < 8; ++p) s += Spart2[(size_t)p * 65536 + t];
  float sq = s * s;
#pragma unroll
  for (int m = 16; m >= 1; m >>= 1) sq += __shfl_xor(sq, m, 64);
  Vout[t] = s * (sq / (1.0f + sq)) * rsqrtf(sq + 1e-8f);
}

extern "C" void kernel_launch(void* const* d_in, const int* in_sizes, int n_in,
                              void* d_out, int out_size, void* d_ws, size_t ws_size,
                              hipStream_t stream) {
  const float* x  = (const float*)d_in[0];
  const float* Kr = (const float*)d_in[1];
  float* ws = (float*)d_ws;
  float* Blog   = ws + WS_BLOG;
  float* Spart  = ws + WS_SPART;
  float* Spart2 = ws + WS_SPART2;
  float* V      = ws + WS_V;
  unsigned short* Ktf = (unsigned short*)(ws + WS_KTF);
  unsigned short* xtf = (unsigned short*)(ws + WS_XTF);
  float* out = (float*)d_out;

  conv_k<<<NIN, 256, 0, stream>>>(Kr, Ktf);
  conv_x<<<1024, 256, 0, stream>>>(x, xtf);

  const dim3 g(256), blk(512);
  caps_mfma<0><<<g, blk, 0, stream>>>(Ktf, xtf, nullptr, Blog, Spart);
  reduce_s1<<<2048, 256, 0, stream>>>(Spart, Spart2);
  reduce_s2<<<256, 256, 0, stream>>>(Spart2, V);
  caps_mfma<1><<<g, blk, 0, stream>>>(Ktf, xtf, V, Blog, Spart);
  reduce_s1<<<2048, 256, 0, stream>>>(Spart, Spart2);
  reduce_s2<<<256, 256, 0, stream>>>(Spart2, V);
  caps_mfma<2><<<g, blk, 0, stream>>>(Ktf, xtf, V, Blog, Spart);
  reduce_s1<<<2048, 256, 0, stream>>>(Spart, Spart2);
  reduce_s2<<<256, 256, 0, stream>>>(Spart2, out);
}